// Round 1
// baseline (2786.565 us; speedup 1.0000x reference)
//
#include <hip/hip_runtime.h>
#include <math.h>

#define NE 1000000
#define DD 128
#define TWOD 256
#define H1C 256
#define H2C 128
#define EB 64
#define EPSLN 1e-5f

#define F4C(v,k) ((k)==0?(v).x:((k)==1?(v).y:((k)==2?(v).z:(v).w)))

__global__ __launch_bounds__(256, 2)
void decoder_fused(const float* __restrict__ nodes,
                   const float* __restrict__ nbrs,
                   const int*   __restrict__ eidx,
                   const float* __restrict__ g0, const float* __restrict__ be0,
                   const float* __restrict__ W1, const float* __restrict__ b1,
                   const float* __restrict__ g1, const float* __restrict__ be1,
                   const float* __restrict__ W2, const float* __restrict__ b2,
                   const float* __restrict__ g2, const float* __restrict__ be2,
                   const float* __restrict__ Wp, const float* __restrict__ bp,
                   const float* __restrict__ Ww, const float* __restrict__ bw,
                   const float* __restrict__ wnode, const float* __restrict__ wnbr,
                   float* __restrict__ out)
{
    __shared__ __align__(16) float xb[EB][TWOD];   // 64 KB staging (x, then h1)
    __shared__ float nbsim[EB];

    const int t    = threadIdx.x;
    const int wv   = t >> 6;     // wave 0..3
    const int lane = t & 63;
    const int rb   = t >> 5;     // 0..7  (row block of 8)
    const int cb   = t & 31;     // 0..31 (col block)
    const int e0   = blockIdx.x * EB;

    // ---------------- Stage 1: gather + combined + LN0 (fused) + nbrs_sim ----
    {
        const int c = 2 * lane;  // this lane's fixed columns: c,c+1 (sum half) / 128+c,129+c (prod half)
        const float2 g0s  = *(const float2*)(g0  + c);
        const float2 g0p  = *(const float2*)(g0  + DD + c);
        const float2 be0s = *(const float2*)(be0 + c);
        const float2 be0p = *(const float2*)(be0 + DD + c);
        #pragma unroll 2
        for (int ee = 0; ee < 16; ++ee) {
            const int el = wv * 16 + ee;
            const int e  = e0 + el;
            const int u  = eidx[e];
            const int v  = eidx[NE + e];
            const float2 nu = *(const float2*)(nodes + u * DD + c);
            const float2 nv = *(const float2*)(nodes + v * DD + c);
            const float2 bu = *(const float2*)(nbrs  + u * DD + c);
            const float2 bv = *(const float2*)(nbrs  + v * DD + c);
            const float sx = nu.x + nv.x, sy = nu.y + nv.y;
            const float px = nu.x * nv.x, py = nu.y * nv.y;
            float ps  = sx + sy + px + py;
            float pss = sx*sx + sy*sy + px*px + py*py;
            float pd  = bu.x * bv.x + bu.y * bv.y;
            #pragma unroll
            for (int m = 1; m < 64; m <<= 1) {
                ps  += __shfl_xor(ps,  m, 64);
                pss += __shfl_xor(pss, m, 64);
                pd  += __shfl_xor(pd,  m, 64);
            }
            const float mu  = ps  * (1.0f / 256.0f);
            const float var = pss * (1.0f / 256.0f) - mu * mu;
            const float inv = 1.0f / sqrtf(var + EPSLN);
            xb[el][c]          = (sx - mu) * inv * g0s.x + be0s.x;
            xb[el][c + 1]      = (sy - mu) * inv * g0s.y + be0s.y;
            xb[el][DD + c]     = (px - mu) * inv * g0p.x + be0p.x;
            xb[el][DD + c + 1] = (py - mu) * inv * g0p.y + be0p.y;
            if (lane == 0) nbsim[el] = pd;
        }
    }
    __syncthreads();

    const int r0 = rb * 8;

    // ---------------- GEMM1: [64,256] @ [256,256], 8x8 register tile ---------
    float acc[8][8];
    #pragma unroll
    for (int i = 0; i < 8; ++i)
        #pragma unroll
        for (int j = 0; j < 8; ++j) acc[i][j] = 0.0f;

    const int c1 = cb * 8;
    for (int k0 = 0; k0 < TWOD; k0 += 4) {
        float4 xv[8];
        #pragma unroll
        for (int i = 0; i < 8; ++i) xv[i] = *(const float4*)&xb[r0 + i][k0];
        #pragma unroll
        for (int kk = 0; kk < 4; ++kk) {
            const float4 wa = *(const float4*)(W1 + (k0 + kk) * H1C + c1);
            const float4 wb4 = *(const float4*)(W1 + (k0 + kk) * H1C + c1 + 4);
            #pragma unroll
            for (int i = 0; i < 8; ++i) {
                const float x = F4C(xv[i], kk);
                acc[i][0] = fmaf(x, wa.x,  acc[i][0]);
                acc[i][1] = fmaf(x, wa.y,  acc[i][1]);
                acc[i][2] = fmaf(x, wa.z,  acc[i][2]);
                acc[i][3] = fmaf(x, wa.w,  acc[i][3]);
                acc[i][4] = fmaf(x, wb4.x, acc[i][4]);
                acc[i][5] = fmaf(x, wb4.y, acc[i][5]);
                acc[i][6] = fmaf(x, wb4.z, acc[i][6]);
                acc[i][7] = fmaf(x, wb4.w, acc[i][7]);
            }
        }
    }
    __syncthreads();   // all GEMM1 reads of xb complete

    // ---------------- bias + LN1 + ReLU, write h1 back into xb ---------------
    {
        const float4 b1a = *(const float4*)(b1  + c1);
        const float4 b1b = *(const float4*)(b1  + c1 + 4);
        const float4 g1a = *(const float4*)(g1  + c1);
        const float4 g1b = *(const float4*)(g1  + c1 + 4);
        const float4 e1a = *(const float4*)(be1 + c1);
        const float4 e1b = *(const float4*)(be1 + c1 + 4);
        #pragma unroll
        for (int i = 0; i < 8; ++i) {
            float v[8];
            v[0] = acc[i][0] + b1a.x; v[1] = acc[i][1] + b1a.y;
            v[2] = acc[i][2] + b1a.z; v[3] = acc[i][3] + b1a.w;
            v[4] = acc[i][4] + b1b.x; v[5] = acc[i][5] + b1b.y;
            v[6] = acc[i][6] + b1b.z; v[7] = acc[i][7] + b1b.w;
            float s = 0.0f, ss = 0.0f;
            #pragma unroll
            for (int j = 0; j < 8; ++j) { s += v[j]; ss += v[j] * v[j]; }
            #pragma unroll
            for (int m = 1; m < 32; m <<= 1) {
                s  += __shfl_xor(s,  m, 32);
                ss += __shfl_xor(ss, m, 32);
            }
            const float mu  = s  * (1.0f / 256.0f);
            const float var = ss * (1.0f / 256.0f) - mu * mu;
            const float inv = 1.0f / sqrtf(var + EPSLN);
            float o[8];
            o[0] = fmaxf(0.0f, (v[0]-mu)*inv*g1a.x + e1a.x);
            o[1] = fmaxf(0.0f, (v[1]-mu)*inv*g1a.y + e1a.y);
            o[2] = fmaxf(0.0f, (v[2]-mu)*inv*g1a.z + e1a.z);
            o[3] = fmaxf(0.0f, (v[3]-mu)*inv*g1a.w + e1a.w);
            o[4] = fmaxf(0.0f, (v[4]-mu)*inv*g1b.x + e1b.x);
            o[5] = fmaxf(0.0f, (v[5]-mu)*inv*g1b.y + e1b.y);
            o[6] = fmaxf(0.0f, (v[6]-mu)*inv*g1b.z + e1b.z);
            o[7] = fmaxf(0.0f, (v[7]-mu)*inv*g1b.w + e1b.w);
            *(float4*)&xb[r0 + i][c1]     = make_float4(o[0], o[1], o[2], o[3]);
            *(float4*)&xb[r0 + i][c1 + 4] = make_float4(o[4], o[5], o[6], o[7]);
        }
    }
    __syncthreads();   // h1 fully written

    // ---------------- GEMM2: [64,256] @ [256,128], 8x4 register tile ---------
    float ac2[8][4];
    #pragma unroll
    for (int i = 0; i < 8; ++i)
        #pragma unroll
        for (int j = 0; j < 4; ++j) ac2[i][j] = 0.0f;

    const int c2 = cb * 4;
    for (int k0 = 0; k0 < TWOD; k0 += 4) {
        float4 xv[8];
        #pragma unroll
        for (int i = 0; i < 8; ++i) xv[i] = *(const float4*)&xb[r0 + i][k0];
        #pragma unroll
        for (int kk = 0; kk < 4; ++kk) {
            const float4 w = *(const float4*)(W2 + (k0 + kk) * H2C + c2);
            #pragma unroll
            for (int i = 0; i < 8; ++i) {
                const float x = F4C(xv[i], kk);
                ac2[i][0] = fmaf(x, w.x, ac2[i][0]);
                ac2[i][1] = fmaf(x, w.y, ac2[i][1]);
                ac2[i][2] = fmaf(x, w.z, ac2[i][2]);
                ac2[i][3] = fmaf(x, w.w, ac2[i][3]);
            }
        }
    }

    // ---------------- bias + LN2 + ReLU + heads + outputs --------------------
    {
        const float4 b2v = *(const float4*)(b2  + c2);
        const float4 g2v = *(const float4*)(g2  + c2);
        const float4 e2v = *(const float4*)(be2 + c2);
        const float4 wpv = *(const float4*)(Wp  + c2);
        const float4 wwv = *(const float4*)(Ww  + c2);
        const float ww128 = Ww[DD];
        const float bpv = bp[0], bwv = bw[0];
        const float wn = wnode[0], wbr = wnbr[0];
        #pragma unroll
        for (int i = 0; i < 8; ++i) {
            float v0 = ac2[i][0] + b2v.x;
            float v1 = ac2[i][1] + b2v.y;
            float v2 = ac2[i][2] + b2v.z;
            float v3 = ac2[i][3] + b2v.w;
            float s  = v0 + v1 + v2 + v3;
            float ss = v0*v0 + v1*v1 + v2*v2 + v3*v3;
            #pragma unroll
            for (int m = 1; m < 32; m <<= 1) {
                s  += __shfl_xor(s,  m, 32);
                ss += __shfl_xor(ss, m, 32);
            }
            const float mu  = s  * (1.0f / 128.0f);
            const float var = ss * (1.0f / 128.0f) - mu * mu;
            const float inv = 1.0f / sqrtf(var + EPSLN);
            const float h0 = fmaxf(0.0f, (v0-mu)*inv*g2v.x + e2v.x);
            const float h1v = fmaxf(0.0f, (v1-mu)*inv*g2v.y + e2v.y);
            const float h2v = fmaxf(0.0f, (v2-mu)*inv*g2v.z + e2v.z);
            const float h3 = fmaxf(0.0f, (v3-mu)*inv*g2v.w + e2v.w);
            float pdot = h0*wpv.x + h1v*wpv.y + h2v*wpv.z + h3*wpv.w;
            float wdot = h0*wwv.x + h1v*wwv.y + h2v*wwv.z + h3*wwv.w;
            #pragma unroll
            for (int m = 1; m < 32; m <<= 1) {
                pdot += __shfl_xor(pdot, m, 32);
                wdot += __shfl_xor(wdot, m, 32);
            }
            if (cb == 0) {
                const int e  = e0 + r0 + i;
                const float ns   = nbsim[r0 + i];
                const float nc   = (pdot + bpv) * wn;
                const float nbc  = ns * wbr;
                const float prob = nc + nbc;
                out[e]          = prob;
                out[NE + e]     = fmaxf(0.0f, wdot + ns * ww128 + bwv);
                out[2 * NE + e] = nc / (prob + 1e-8f);
            }
        }
    }
}

extern "C" void kernel_launch(void* const* d_in, const int* in_sizes, int n_in,
                              void* d_out, int out_size, void* d_ws, size_t ws_size,
                              hipStream_t stream) {
    const float* nodes = (const float*)d_in[0];
    const float* nbrs  = (const float*)d_in[1];
    const int*   eidx  = (const int*)d_in[2];
    const float* g0    = (const float*)d_in[3];
    const float* be0   = (const float*)d_in[4];
    const float* W1    = (const float*)d_in[5];
    const float* b1    = (const float*)d_in[6];
    const float* g1    = (const float*)d_in[7];
    const float* be1   = (const float*)d_in[8];
    const float* W2    = (const float*)d_in[9];
    const float* b2    = (const float*)d_in[10];
    const float* g2    = (const float*)d_in[11];
    const float* be2   = (const float*)d_in[12];
    const float* Wp    = (const float*)d_in[13];
    const float* bp    = (const float*)d_in[14];
    const float* Ww    = (const float*)d_in[15];
    const float* bw    = (const float*)d_in[16];
    const float* wnode = (const float*)d_in[17];
    const float* wnbr  = (const float*)d_in[18];
    float* out = (float*)d_out;

    dim3 grid(NE / EB), block(256);
    decoder_fused<<<grid, block, 0, stream>>>(nodes, nbrs, eidx, g0, be0,
                                              W1, b1, g1, be1, W2, b2, g2, be2,
                                              Wp, bp, Ww, bw, wnode, wnbr, out);
}